// Round 4
// baseline (621.466 us; speedup 1.0000x reference)
//
#include <hip/hip_runtime.h>
#include <hip/hip_bf16.h>

// Problem constants
#define H_ 8
#define D_ 512
#define DK_ 64
#define B_ 16
#define N_ 8192
#define M_ (B_ * N_)  // 131072 rows

typedef __attribute__((ext_vector_type(8))) short short8;
typedef __attribute__((ext_vector_type(4))) float floatx4;

// ---------------------------------------------------------------- helpers
__device__ __forceinline__ void glds16(const void* g, void* l) {
    // 16B-wide direct global->LDS DMA. LDS dest = wave-uniform base + lane*16.
    __builtin_amdgcn_global_load_lds((const __attribute__((address_space(1))) void*)g,
                                     (__attribute__((address_space(3))) void*)l,
                                     16, 0, 0);
}

__device__ __forceinline__ unsigned short f2bf(float f) {  // RNE
    unsigned u = __float_as_uint(f);
    return (unsigned short)((u + 0x7fffu + ((u >> 16) & 1u)) >> 16);
}

// pack two fp32 -> two bf16 (round-half-up): low16 = bf(x), high16 = bf(y)
__device__ __forceinline__ unsigned pack_bf2(float x, float y) {
    return __builtin_amdgcn_perm(__float_as_uint(y) + 0x8000u,
                                 __float_as_uint(x) + 0x8000u, 0x07060302u);
}

__device__ __forceinline__ short8 pack_bf8(float4 lo, float4 hi) {
    union { unsigned u[4]; short8 s; } tmp;
    tmp.u[0] = pack_bf2(lo.x, lo.y);
    tmp.u[1] = pack_bf2(lo.z, lo.w);
    tmp.u[2] = pack_bf2(hi.x, hi.y);
    tmp.u[3] = pack_bf2(hi.z, hi.w);
    return tmp.s;
}

// ---------------------------------------------------------------- kernel 0: both weight matrices fp32 -> bf16
__global__ __launch_bounds__(256) void cvt2_kernel(const float* __restrict__ s0,
                                                   const float* __restrict__ s1,
                                                   unsigned short* __restrict__ d0,
                                                   unsigned short* __restrict__ d1) {
    const int blk = blockIdx.x;
    const float* src = (blk < 256) ? s0 : s1;
    unsigned short* dst = (blk < 256) ? d0 : d1;
    int i = (blk & 255) * 256 + threadIdx.x;  // 65536 float4 per matrix
    float4 v = ((const float4*)src)[i];
    ushort4 o;
    o.x = f2bf(v.x); o.y = f2bf(v.y); o.z = f2bf(v.z); o.w = f2bf(v.w);
    ((ushort4*)dst)[i] = o;
}

// ---------------------------------------------------------------- kernel 1: fused double-GEMM + gate + query-dot
// BM=128, BN=128 (2 heads), BK=32, 256 threads, wave -> 64x64 quadrant.
// Fully double-buffered 1-barrier pipeline: every global op gets an MFMA
// phase before the barrier's vmcnt(0) drain touches it.
// Swizzle: 16B chunk c of row r at slot c ^ ((r>>1)&3)  (4 slots/row).
__global__ __launch_bounds__(256, 2) void gemm_score_kernel(
    const float* __restrict__ x,             // (M_, 512) fp32
    const unsigned short* __restrict__ wkb,  // (512, 512) bf16
    const unsigned short* __restrict__ wgb,  // (512, 512) bf16
    const float* __restrict__ query,         // (8, 64) fp32
    float* __restrict__ s_buf)               // (B_, H_, N_) fp32
{
    // 6 buffers x 8 KB = 48 KB: a0,a1,k0,k1,g0,g1
    __shared__ unsigned short lds[6][128 * 32];

    const int t = threadIdx.x;
    const int lane = t & 63;
    const int wave = t >> 6;
    const int wm = wave >> 1, wn = wave & 1;

    // XCD-aware remap: the 4 jc-siblings of an m-tile share an XCD (L2 reuse of A).
    const int g = blockIdx.x;              // 0..4095
    const int xcd = g & 7;
    const int s = g >> 3;                  // 0..511
    const int jt = s & 3;                  // jc tile 0..3
    const int mt = ((s >> 2) << 3) | xcd;  // 0..1023
    const int jc = jt * 128;
    const int m0 = mt * 128;

    floatx4 acc_k[4][4], acc_g[4][4];
#pragma unroll
    for (int i = 0; i < 4; ++i)
#pragma unroll
        for (int j = 0; j < 4; ++j) { acc_k[i][j] = (floatx4)0.f; acc_g[i][j] = (floatx4)0.f; }

    // ---- A staging: thread t -> row r = t>>1, 16 k-elems at (t&1)*16 (4 float4)
    const int ar = t >> 1;
    const int ac0 = (t & 1) * 2;                       // first 16B-bf16 chunk index
    const int aswr = (ar >> 1) & 3;
    const float* pA = x + (size_t)(m0 + ar) * 512 + (t & 1) * 16;
    const int ao0 = (ar * 4 + (ac0 ^ aswr)) * 8;       // ushort offsets in LDS
    const int ao1 = (ar * 4 + ((ac0 + 1) ^ aswr)) * 8;

    // ---- B staging: slots p = t, 256+t; slot p holds chunk (r=p>>2, c=(p&3)^((r>>1)&3))
    int boff[2];
#pragma unroll
    for (int i = 0; i < 2; ++i) {
        int p = i * 256 + t;
        int r = p >> 2;
        int c = (p & 3) ^ ((r >> 1) & 3);
        boff[i] = (jc + r) * 512 + c * 8;  // bf16 elements (+k0 at use)
    }

    // ---- fragment reads: lane (q, fr) -> row fr, slot q ^ ((fr>>1)&3)
    const int fr = lane & 15;
    const int q  = lane >> 4;
    const int slq = (q ^ ((fr >> 1) & 3)) * 8;  // ushort offset within row

    // ---- prologue: stage tile 0 into parity-0 buffers
#pragma unroll
    for (int i = 0; i < 2; ++i) {
        glds16(wkb + boff[i], &lds[2][(i * 256 + t) * 8]);
        glds16(wgb + boff[i], &lds[4][(i * 256 + t) * 8]);
    }
    {
        float4 f0 = *(const float4*)(pA + 0);
        float4 f1 = *(const float4*)(pA + 4);
        float4 f2 = *(const float4*)(pA + 8);
        float4 f3 = *(const float4*)(pA + 12);
        *(short8*)&lds[0][ao0] = pack_bf8(f0, f1);
        *(short8*)&lds[0][ao1] = pack_bf8(f2, f3);
    }
    __syncthreads();

#pragma unroll
    for (int k = 0; k < 16; ++k) {
        const int cur = k & 1, nxt = cur ^ 1;
        float4 f0, f1, f2, f3;
        if (k < 15) {
            const int k1 = (k + 1) * 32;
            // B(k+1): async DMA into next buffers (free: last read at iter k-1)
#pragma unroll
            for (int i = 0; i < 2; ++i) {
                glds16(wkb + boff[i] + k1, &lds[2 + nxt][(i * 256 + t) * 8]);
                glds16(wgb + boff[i] + k1, &lds[4 + nxt][(i * 256 + t) * 8]);
            }
            // A(k+1): global -> regs (consumed after the MFMA phase below)
            f0 = *(const float4*)(pA + k1 + 0);
            f1 = *(const float4*)(pA + k1 + 4);
            f2 = *(const float4*)(pA + k1 + 8);
            f3 = *(const float4*)(pA + k1 + 12);
        }

        // ---- MFMA phase on current buffers
        short8 a[4], bk[4], bg[4];
#pragma unroll
        for (int mi = 0; mi < 4; ++mi)
            a[mi] = *(const short8*)(&lds[cur][(wm * 64 + mi * 16 + fr) * 32 + slq]);
#pragma unroll
        for (int ni = 0; ni < 4; ++ni) {
            bk[ni] = *(const short8*)(&lds[2 + cur][(wn * 64 + ni * 16 + fr) * 32 + slq]);
            bg[ni] = *(const short8*)(&lds[4 + cur][(wn * 64 + ni * 16 + fr) * 32 + slq]);
        }
#pragma unroll
        for (int mi = 0; mi < 4; ++mi)
#pragma unroll
            for (int ni = 0; ni < 4; ++ni) {
                acc_k[mi][ni] = __builtin_amdgcn_mfma_f32_16x16x32_bf16(a[mi], bk[ni], acc_k[mi][ni], 0, 0, 0);
                acc_g[mi][ni] = __builtin_amdgcn_mfma_f32_16x16x32_bf16(a[mi], bg[ni], acc_g[mi][ni], 0, 0, 0);
            }

        if (k < 15) {
            // pack A(k+1) -> next A buffer (vmcnt wait was covered by MFMA phase)
            *(short8*)&lds[nxt][ao0] = pack_bf8(f0, f1);
            *(short8*)&lds[nxt][ao1] = pack_bf8(f2, f3);
            __syncthreads();  // publishes A writes; drains B DMA (covered by MFMA)
        }
    }

    // Epilogue: gated = tanh(K)*sigmoid(G); score = q . gated, reduce over 16 lanes.
    // C/D layout: col = lane&15, row = (lane>>4)*4 + reg.
    const int h = jt * 2 + wn;
    float qv[4];
#pragma unroll
    for (int ni = 0; ni < 4; ++ni) qv[ni] = query[h * 64 + ni * 16 + fr];

#pragma unroll
    for (int mi = 0; mi < 4; ++mi) {
#pragma unroll
        for (int r = 0; r < 4; ++r) {
            float v = 0.f;
#pragma unroll
            for (int ni = 0; ni < 4; ++ni) {
                float kv = acc_k[mi][ni][r];
                float gv = acc_g[mi][ni][r];
                float e2k = __expf(2.f * kv);
                float th = 1.f - 2.f / (e2k + 1.f);       // tanh, overflow-safe
                float sg = 1.f / (1.f + __expf(-gv));     // sigmoid
                v += qv[ni] * th * sg;
            }
            v += __shfl_xor(v, 1);
            v += __shfl_xor(v, 2);
            v += __shfl_xor(v, 4);
            v += __shfl_xor(v, 8);
            if (fr == 0) {
                int mg = m0 + wm * 64 + mi * 16 + (lane >> 4) * 4 + r;
                int b = mg >> 13, n = mg & 8191;
                s_buf[((size_t)(b * 8 + h) << 13) + n] = v;
            }
        }
    }
}

// ---------------------------------------------------------------- kernel 2: per-(b,h) softmax stats
__global__ __launch_bounds__(256) void stats_kernel(const float* __restrict__ s_buf,
                                                    float* __restrict__ mb, float* __restrict__ lb) {
    const int bh = blockIdx.x;  // 0..127
    const float* s = s_buf + ((size_t)bh << 13);
    const int t = threadIdx.x;
    float mx = -3.0e38f;
    for (int i = t; i < 8192; i += 256) mx = fmaxf(mx, s[i]);
#pragma unroll
    for (int m = 32; m > 0; m >>= 1) mx = fmaxf(mx, __shfl_xor(mx, m));
    __shared__ float red[8];
    if ((t & 63) == 0) red[t >> 6] = mx;
    __syncthreads();
    mx = fmaxf(fmaxf(red[0], red[1]), fmaxf(red[2], red[3]));
    float sum = 0.f;
    for (int i = t; i < 8192; i += 256) sum += __expf(s[i] - mx);
#pragma unroll
    for (int m = 32; m > 0; m >>= 1) sum += __shfl_xor(sum, m);
    if ((t & 63) == 0) red[4 + (t >> 6)] = sum;
    __syncthreads();
    if (t == 0) { mb[bh] = mx; lb[bh] = red[4] + red[5] + red[6] + red[7]; }
}

// ---------------------------------------------------------------- kernel 3a: partial weighted sums (no atomics)
// part[(b*32+chunk)*4 + rg][512]
__global__ __launch_bounds__(256) void out_part_kernel(
    const float* __restrict__ x, const float* __restrict__ s_buf,
    const float* __restrict__ mb, const float* __restrict__ lb,
    float* __restrict__ part) {
    const int b = blockIdx.x >> 5;      // 16
    const int chunk = blockIdx.x & 31;  // 32 chunks of 256 rows
    const int n0 = chunk * 256;
    const int t = threadIdx.x;
    __shared__ float w[8 * 256];
    for (int i = t; i < 2048; i += 256) {
        int hh = i >> 8, nn = i & 255;
        int bh = b * 8 + hh;
        w[i] = __expf(s_buf[((size_t)bh << 13) + n0 + nn] - mb[bh]) / lb[bh];
    }
    __syncthreads();
    const int rg = t >> 6;            // 4 row-groups (disjoint rows)
    const int d0 = (t & 63) * 8;      // 8 fp32 per thread -> full 512-wide row per wave
    const float* wh = w + ((d0 >> 6) << 8);
    float acc[8] = {0.f, 0.f, 0.f, 0.f, 0.f, 0.f, 0.f, 0.f};
    for (int nn = rg; nn < 256; nn += 4) {
        const float4* row = (const float4*)(x + (((size_t)(b * 8192 + n0 + nn)) << 9) + d0);
        float4 v0 = row[0];
        float4 v1 = row[1];
        float ww = wh[nn];
        acc[0] += ww * v0.x; acc[1] += ww * v0.y;
        acc[2] += ww * v0.z; acc[3] += ww * v0.w;
        acc[4] += ww * v1.x; acc[5] += ww * v1.y;
        acc[6] += ww * v1.z; acc[7] += ww * v1.w;
    }
    float* dst = part + ((size_t)(blockIdx.x * 4 + rg)) * 512 + d0;
    *(float4*)(dst)     = make_float4(acc[0], acc[1], acc[2], acc[3]);
    *(float4*)(dst + 4) = make_float4(acc[4], acc[5], acc[6], acc[7]);
}

// ---------------------------------------------------------------- kernel 3b: reduce partials -> out
__global__ __launch_bounds__(512) void out_reduce_kernel(const float* __restrict__ part,
                                                         float* __restrict__ out) {
    const int b = blockIdx.x;   // 16
    const int d = threadIdx.x;  // 512
    float s = 0.f;
    const float* p = part + (size_t)b * 128 * 512 + d;
    for (int i = 0; i < 128; ++i) s += p[(size_t)i * 512];
    out[b * 512 + d] = s;
}

// ---------------------------------------------------------------- launch
extern "C" void kernel_launch(void* const* d_in, const int* in_sizes, int n_in,
                              void* d_out, int out_size, void* d_ws, size_t ws_size,
                              hipStream_t stream) {
    const float* x  = (const float*)d_in[0];
    const float* Wk = (const float*)d_in[1];
    const float* Wg = (const float*)d_in[2];
    const float* q  = (const float*)d_in[3];
    float* out = (float*)d_out;

    // ws layout (~9.25 MB)
    char* ws = (char*)d_ws;
    unsigned short* wkb = (unsigned short*)ws;                   // 524288 B
    unsigned short* wgb = (unsigned short*)(ws + 524288ull);     // 524288 B
    float* s_buf = (float*)(ws + 1048576ull);                    // 4194304 B
    float* part  = (float*)(ws + 5242880ull);                    // 4194304 B (2048x512 fl)
    float* mb = (float*)(ws + 9437184ull);                       // 512 B
    float* lb = (float*)(ws + 9437696ull);                       // 512 B

    hipLaunchKernelGGL(cvt2_kernel, dim3(512), dim3(256), 0, stream, Wk, Wg, wkb, wgb);
    hipLaunchKernelGGL(gemm_score_kernel, dim3(4096), dim3(256), 0, stream, x, wkb, wgb, q, s_buf);
    hipLaunchKernelGGL(stats_kernel, dim3(128), dim3(256), 0, stream, s_buf, mb, lb);
    hipLaunchKernelGGL(out_part_kernel, dim3(512), dim3(256), 0, stream, x, s_buf, mb, lb, part);
    hipLaunchKernelGGL(out_reduce_kernel, dim3(16), dim3(512), 0, stream, part, out);
}